// Round 6
// baseline (81.853 us; speedup 1.0000x reference)
//
#include <hip/hip_runtime.h>

#define GX 192
#define GY 96
#define GZ 192
#define GRP (GY*GZ)            // 18432 (y,z) groups
#define NVOX (GX*GRP)          // 3538944 voxels

#define NXC 12                 // x-chunks
#define XCW (GX/NXC)           // 16 voxels per thread/chunk
#define GBLK (GRP/256)         // 72 blocks per chunk

#define K2T 1024               // select kernel threads
#define GPT (GRP/K2T)          // 18 groups per thread
#define WBINS 4096             // window chunk bins (16-bit pass)
#define BPT (WBINS/K2T)        // 4 bins per thread

// workspace byte offsets
#define WS_MVP    0                        // 16 floats
#define WS_DEPTH  64                       // GRP u32 depth bits
#define WS_MASK   (WS_DEPTH + GRP*4)       // NXC x GRP u16 validity bitmask
#define WS_SEL    (WS_MASK + NXC*GRP*2)    // 2 u32: T, R
#define WS_TLIST  (WS_SEL + 16)            // 256 u32 tied group ids (sorted)
#define WS_TPREF  (WS_TLIST + 1024)        // GX u32 excl prefix of tied-valid per x
#define WS_NTIED  (WS_TPREF + GX*4)        // 1 u32

typedef float f4 __attribute__((ext_vector_type(4)));

// Replicate reference fp32 arithmetic exactly:
//   clip_c = fma(cz, M[c][2], fma(cy, M[c][1], cx*M[c][0])) + M[c][3]
__device__ __forceinline__ bool voxel_valid(int x, int g,
                                            const float* __restrict__ occL,
                                            const float* M,
                                            float* occ_out)
{
    int y = g / GZ;
    int z = g - y * GZ;
    float cx = (float)(2 * x - 191);
    float cy = (float)(2 * y + 1);
    float cz = (float)(2 * z - 191);

    float logit = occL[(size_t)x * GRP + g];
    float occ = 1.0f / (1.0f + expf(-logit));
    *occ_out = occ;
    if (!(occ > 0.01f)) return false;

    float c0 = __fadd_rn(__fmaf_rn(cz, M[2],  __fmaf_rn(cy, M[1],  __fmul_rn(cx, M[0]))),  M[3]);
    float c1 = __fadd_rn(__fmaf_rn(cz, M[6],  __fmaf_rn(cy, M[5],  __fmul_rn(cx, M[4]))),  M[7]);
    float c2 = __fadd_rn(__fmaf_rn(cz, M[10], __fmaf_rn(cy, M[9],  __fmul_rn(cx, M[8]))),  M[11]);
    float c3 = __fadd_rn(__fmaf_rn(cz, M[14], __fmaf_rn(cy, M[13], __fmul_rn(cx, M[12]))), M[15]);

    float w  = fmaxf(c3, 1e-6f);
    float nx = c0 / w;
    float ny = c1 / w;
    float nz = c2 / w;
    return (nx >= -1.0f) && (nx <= 1.0f) &&
           (ny >= -1.0f) && (ny <= 1.0f) &&
           (nz >= -1.0f) && (nz <= 1.0f);
}

__device__ __forceinline__ void compute_mvp_lds(const float* view, const float* proj,
                                                float* s_mvp, int tid)
{
    if (tid < 16) {
        int r = tid >> 2, c = tid & 3;
        float acc = 0.0f;
        for (int k = 0; k < 4; ++k)
            acc = __fadd_rn(acc, __fmul_rn(proj[r * 4 + k], view[k * 4 + c]));
        s_mvp[tid] = acc;
    }
}

__device__ __forceinline__ unsigned wave_incl_scan(unsigned v, int lane)
{
    #pragma unroll
    for (int off = 1; off < 64; off <<= 1) {
        unsigned u = (unsigned)__shfl_up((int)v, off);
        if (lane >= off) v += u;
    }
    return v;
}

// K1: mvp (block 0 -> ws), depth bits (xc==0), u16 validity mask per (xc, g).
// grid = NXC * GBLK = 864 blocks of 256. Sole evaluator of voxel_valid.
__global__ __launch_bounds__(256) void k_prep_count(
    const float* __restrict__ view, const float* __restrict__ proj,
    const float* __restrict__ occL,
    float* __restrict__ mvpOut,
    unsigned* __restrict__ depthBits,
    unsigned short* __restrict__ mask16)
{
    __shared__ float s_mvp[16];
    int tid = threadIdx.x;
    compute_mvp_lds(view, proj, s_mvp, tid);
    __syncthreads();

    int b  = blockIdx.x;
    int gb = b % GBLK;
    int xc = b / GBLK;
    int g  = gb * 256 + tid;

    if (b == 0 && tid < 16) mvpOut[tid] = s_mvp[tid];

    if (xc == 0) {
        int y = g / GZ;
        int z = g - y * GZ;
        float cy = (float)(2 * y + 1);
        float cz = (float)(2 * z - 191);
        float seed = __fmul_rn(-191.0f, view[8]);
        float vz = __fadd_rn(__fmaf_rn(cz, view[10], __fmaf_rn(cy, view[9], seed)), view[11]);
        float d  = fmaxf(-vz, 0.0f);
        depthBits[g] = __float_as_uint(d);   // d >= 0: bits order-monotone
    }

    unsigned m = 0;
    int x0 = xc * XCW;
    #pragma unroll
    for (int j = 0; j < XCW; ++j) {
        float occ;
        if (voxel_valid(x0 + j, g, occL, s_mvp, &occ)) m |= (1u << j);
    }
    mask16[(size_t)xc * GRP + g] = (unsigned short)m;
}

// K2: full weighted selection + tied-group prep in ONE block of 1024 threads.
// Counts come from popcounting the mask; tie-prefix from mask bits.
// Integer-identical to the verified radix walk: 16-bit windowed pass + 2x 8-bit.
__global__ __launch_bounds__(1024) void k_select(
    const unsigned* __restrict__ depthBits,
    const unsigned short* __restrict__ mask16,
    const int* __restrict__ maxBlocksPtr,
    unsigned* __restrict__ sel,
    unsigned* __restrict__ tiedList,
    unsigned* __restrict__ tiedPrefX,
    unsigned* __restrict__ nTiedG)
{
    __shared__ unsigned s_h[WBINS];      // 16 KB hist (reused for 256-bin passes)
    __shared__ unsigned s_w[16];         // wave partials / offsets
    __shared__ unsigned s_wT[16], s_wMn[16], s_wMx[16];
    __shared__ unsigned s_tot, s_mn, s_mx, s_chTot;
    __shared__ unsigned s_found, s_prefix, s_remK;
    __shared__ unsigned s_list[256];
    __shared__ int s_n;
    __shared__ unsigned s_cntX[GX];

    int tid  = threadIdx.x;
    int lane = tid & 63;
    int wid  = tid >> 6;

    // ---- load all (depth, cnt) pairs into registers (static indexing) ----
    unsigned d[GPT], c[GPT];
    #pragma unroll
    for (int k = 0; k < GPT; ++k) {
        int g = tid + k * K2T;
        d[k] = depthBits[g];
        unsigned cc = 0;
        #pragma unroll
        for (int xc = 0; xc < NXC; ++xc)
            cc += __popc((unsigned)mask16[(size_t)xc * GRP + g]);
        c[k] = cc;
    }

    // ---- reduce: total valid, min/max of top-16 depth bits (weighted) ----
    unsigned tot = 0, mn = 0xFFFFFFFFu, mx = 0;
    #pragma unroll
    for (int k = 0; k < GPT; ++k) {
        tot += c[k];
        if (c[k]) {
            unsigned hi = d[k] >> 16;
            mn = min(mn, hi);
            mx = max(mx, hi);
        }
    }
    for (int m = 1; m < 64; m <<= 1) {
        tot += (unsigned)__shfl_xor((int)tot, m);
        mn = min(mn, (unsigned)__shfl_xor((int)mn, m));
        mx = max(mx, (unsigned)__shfl_xor((int)mx, m));
    }
    if (lane == 0) { s_wT[wid] = tot; s_wMn[wid] = mn; s_wMx[wid] = mx; }
    __syncthreads();
    if (tid == 0) {
        unsigned t2 = 0, m2 = 0xFFFFFFFFu, x2 = 0;
        for (int w = 0; w < 16; ++w) {
            t2 += s_wT[w]; m2 = min(m2, s_wMn[w]); x2 = max(x2, s_wMx[w]);
        }
        s_tot = t2; s_mn = m2; s_mx = x2;
        s_found = 0;
    }
    __syncthreads();
    unsigned K = (unsigned)maxBlocksPtr[0];
    tot = s_tot; mn = s_mn; mx = s_mx;

    if (tot <= K) {                         // keep all valid
        if (tid == 0) {
            sel[0] = 0xFFFFFFFFu;
            sel[1] = 0x7FFFFFFFu;
            *nTiedG = 0u;
        }
        return;                             // uniform exit
    }

    // ---- pass A: 16-bit windowed histogram, chunks of WBINS ----
    unsigned remK = K;
    unsigned prefix = 0;
    unsigned span = mx - mn + 1u;
    unsigned nchunks = (span + WBINS - 1u) / WBINS;
    for (unsigned ch = 0; ch < nchunks; ++ch) {
        unsigned base = mn + ch * WBINS;
        #pragma unroll
        for (int j = 0; j < BPT; ++j) s_h[tid + j * K2T] = 0;
        __syncthreads();
        #pragma unroll
        for (int k = 0; k < GPT; ++k) {
            if (c[k]) {
                unsigned hi = d[k] >> 16;
                if (hi >= base && hi < base + WBINS)
                    atomicAdd(&s_h[hi - base], c[k]);
            }
        }
        __syncthreads();
        unsigned ps = 0;
        #pragma unroll
        for (int j = 0; j < BPT; ++j) ps += s_h[tid * BPT + j];
        unsigned iw = wave_incl_scan(ps, lane);
        if (lane == 63) s_w[wid] = iw;
        __syncthreads();
        if (wid == 0) {
            unsigned wv = (lane < 16) ? s_w[lane] : 0u;
            unsigned wiw = wave_incl_scan(wv, lane);
            if (lane < 16) s_w[lane] = wiw - wv;   // exclusive wave offset
            if (lane == 15) s_chTot = wiw;         // chunk total
        }
        __syncthreads();
        unsigned incl = iw + s_w[wid];
        unsigned chunkTot = s_chTot;
        unsigned excl = incl - ps;
        if (remK <= chunkTot && excl < remK && remK <= incl) {
            unsigned cum = excl;
            #pragma unroll
            for (int j = 0; j < BPT; ++j) {
                unsigned hv = s_h[tid * BPT + j];
                if (cum < remK && remK <= cum + hv) {
                    s_found  = 1u;
                    s_prefix = base + (unsigned)(tid * BPT + j);
                    s_remK   = remK - cum;
                }
                cum += hv;
            }
        }
        __syncthreads();
        if (s_found) { prefix = s_prefix; remK = s_remK; break; }
        remK -= chunkTot;                   // uniform
        __syncthreads();
    }

    // ---- passes B, C: 8-bit refine (bits 15..8 then 7..0) ----
    for (int p = 0; p < 2; ++p) {
        int matchShift = (p == 0) ? 16 : 8;
        int digitShift = (p == 0) ? 8 : 0;
        if (tid < 256) s_h[tid] = 0;
        __syncthreads();
        #pragma unroll
        for (int k = 0; k < GPT; ++k) {
            if (c[k] && (d[k] >> matchShift) == prefix)
                atomicAdd(&s_h[(d[k] >> digitShift) & 255u], c[k]);
        }
        __syncthreads();
        unsigned ps = (tid < 256) ? s_h[tid] : 0u;
        unsigned iw = wave_incl_scan(ps, lane);
        if (lane == 63) s_w[wid] = iw;
        __syncthreads();
        if (wid == 0) {
            unsigned wv = (lane < 16) ? s_w[lane] : 0u;
            unsigned wiw = wave_incl_scan(wv, lane);
            if (lane < 16) s_w[lane] = wiw - wv;
        }
        __syncthreads();
        unsigned incl = iw + s_w[wid];
        unsigned excl = incl - ps;
        if (excl < remK && remK <= incl) {   // unique crossing thread (tid<256)
            s_prefix = (prefix << 8) | (unsigned)tid;
            s_remK   = remK - excl;
        }
        __syncthreads();
        prefix = s_prefix; remK = s_remK;
        __syncthreads();
    }
    unsigned T = prefix;                     // final threshold depth bits
    unsigned R = remK;                       // quota at exactly T

    // ---- tied groups: list (sorted), per-x valid prefix (from mask bits) ----
    if (tid == 0) s_n = 0;
    for (int x = tid; x < GX; x += K2T) s_cntX[x] = 0;
    __syncthreads();
    #pragma unroll
    for (int k = 0; k < GPT; ++k) {
        if (d[k] == T) {
            int idx = atomicAdd(&s_n, 1);
            if (idx < 256) s_list[idx] = (unsigned)(tid + k * K2T);
        }
    }
    __syncthreads();
    int n = min(s_n, 256);
    if (tid == 0) {
        for (int a = 1; a < n; ++a) {        // insertion sort (n tiny)
            unsigned v = s_list[a];
            int b = a - 1;
            while (b >= 0 && s_list[b] > v) { s_list[b + 1] = s_list[b]; --b; }
            s_list[b + 1] = v;
        }
    }
    __syncthreads();
    int pairs = GX * n;
    for (int pr = tid; pr < pairs; pr += K2T) {
        int x = pr / n;
        int s = pr - x * n;
        unsigned gs = s_list[s];
        if ((mask16[(size_t)(x >> 4) * GRP + gs] >> (x & 15)) & 1u)
            atomicAdd(&s_cntX[x], 1u);
    }
    __syncthreads();
    if (tid == 0) {
        unsigned run = 0;
        for (int x = 0; x < GX; ++x) { tiedPrefX[x] = run; run += s_cntX[x]; }
        *nTiedG = (unsigned)n;
        sel[0] = T;
        sel[1] = R;
    }
    if (tid < n) tiedList[tid] = s_list[tid];
}

// K3: output. Reads mask bit + depth; gathers occ/materials only for kept voxels.
__global__ __launch_bounds__(256) void k_out(
    const float* __restrict__ occL,
    const float* __restrict__ matL,
    const unsigned* __restrict__ depthBits,
    const unsigned short* __restrict__ mask16,
    const unsigned* __restrict__ sel,
    const unsigned* __restrict__ tiedList,
    const unsigned* __restrict__ tiedPrefX,
    const unsigned* __restrict__ nTiedPtr,
    float* __restrict__ out)
{
    int i = blockIdx.x * 256 + threadIdx.x;
    if (i >= NVOX) return;
    int x = i / GRP;                       // wave-uniform (GRP % 256 == 0)
    int g = i - x * GRP;

    bool valid = (mask16[(size_t)(x >> 4) * GRP + g] >> (x & 15)) & 1u;
    bool keep = false;
    if (valid) {
        unsigned T  = sel[0];
        unsigned db = depthBits[g];
        if (db < T) {
            keep = true;
        } else if (db == T) {
            unsigned R = sel[1];
            unsigned rank = tiedPrefX[x];
            int n = (int)*nTiedPtr;
            for (int s = 0; s < n; ++s) {
                unsigned gs = tiedList[s];
                if (gs >= (unsigned)g) break;
                rank += (mask16[(size_t)(x >> 4) * GRP + gs] >> (x & 15)) & 1u;
            }
            keep = rank < R;
        }
    }

    f4 o0 = (f4)(0.0f);
    f4 o1 = (f4)(0.0f);
    if (keep) {
        float logit = occL[i];
        float occ = 1.0f / (1.0f + expf(-logit));   // identical expression
        const f4* mp = reinterpret_cast<const f4*>(matL) + (size_t)i * 2;
        f4 a = mp[0];
        f4 b = mp[1];
        float mx = fmaxf(fmaxf(fmaxf(a[0], a[1]), fmaxf(a[2], a[3])),
                         fmaxf(fmaxf(b[0], b[1]), fmaxf(b[2], b[3])));
        float e0 = expf(a[0] - mx), e1 = expf(a[1] - mx), e2 = expf(a[2] - mx), e3 = expf(a[3] - mx);
        float e4 = expf(b[0] - mx), e5 = expf(b[1] - mx), e6 = expf(b[2] - mx), e7 = expf(b[3] - mx);
        float s = ((e0 + e1) + (e2 + e3)) + ((e4 + e5) + (e6 + e7));
        float inv = occ / s;
        o0[0] = e0 * inv; o0[1] = e1 * inv; o0[2] = e2 * inv; o0[3] = e3 * inv;
        o1[0] = e4 * inv; o1[1] = e5 * inv; o1[2] = e6 * inv; o1[3] = e7 * inv;
    }
    f4* op = reinterpret_cast<f4*>(out) + (size_t)i * 2;
    __builtin_nontemporal_store(o0, op);
    __builtin_nontemporal_store(o1, op + 1);
}

extern "C" void kernel_launch(void* const* d_in, const int* in_sizes, int n_in,
                              void* d_out, int out_size, void* d_ws, size_t ws_size,
                              hipStream_t stream)
{
    const float* occL = (const float*)d_in[0];
    const float* matL = (const float*)d_in[1];
    const float* view = (const float*)d_in[2];
    const float* proj = (const float*)d_in[3];
    const int*   mb   = (const int*)d_in[4];

    char* ws = (char*)d_ws;
    float*          mvp      = (float*)(ws + WS_MVP);
    unsigned*       depthB   = (unsigned*)(ws + WS_DEPTH);
    unsigned short* mask16   = (unsigned short*)(ws + WS_MASK);
    unsigned*       sel      = (unsigned*)(ws + WS_SEL);
    unsigned*       tiedList = (unsigned*)(ws + WS_TLIST);
    unsigned*       tiedPref = (unsigned*)(ws + WS_TPREF);
    unsigned*       nTied    = (unsigned*)(ws + WS_NTIED);

    k_prep_count<<<NXC * GBLK, 256, 0, stream>>>(view, proj, occL, mvp, depthB, mask16);
    k_select<<<1, K2T, 0, stream>>>(depthB, mask16, mb, sel, tiedList, tiedPref, nTied);
    k_out<<<NVOX / 256, 256, 0, stream>>>(occL, matL, depthB, mask16, sel,
                                          tiedList, tiedPref, nTied, (float*)d_out);
}